// Round 10
// baseline (340.757 us; speedup 1.0000x reference)
//
#include <hip/hip_runtime.h>

typedef _Float16 half8 __attribute__((ext_vector_type(8)));
typedef float f32x16 __attribute__((ext_vector_type(16)));
typedef float f32x4 __attribute__((ext_vector_type(4)));

#define N_IMG 32
#define C_IN  128
#define H_IN  56
#define W_IN  56
#define F_OUT 256
#define HO    54
#define WO    54
#define KKDIM 1152
#define NKB   18            // 1152 / 64

#define T2_BYTES (N_IMG * W_IN * H_IN * C_IN * 2)   // 25,690,112
#define BP_OFF   T2_BYTES
#define BP_BYTES (NKB * F_OUT * 64 * 2)             // 589,824
#define WS_NEED  (BP_OFF + BP_BYTES)

#define SLAB_I_STRIDE 14336        // 56 rows * 256 B
#define A_REGION  88576            // padded (h>=54 garbage rows, discarded)
#define B_CHUNK   32768
#define SMEM_BYTES (A_REGION + 2 * B_CHUNK)  // 154112

#define ASM_BAR() asm volatile("s_barrier" ::: "memory")

static __device__ inline unsigned pack2(float a, float b) {
    union { _Float16 h[2]; unsigned u; } x;
    x.h[0] = (_Float16)a; x.h[1] = (_Float16)b; return x.u;
}

// ---------------------------------------------------------------------------
// Kernel 1 v2: NCHW fp32 -> T2[n][ww][hh][c] fp16 (T2 slot j holds c-group
// j^(hh&15), same convention as before — k_gemm untouched).
// Block = (hh-quad, n), 256 thr. Phase A: float4 loads (coalesced 896B/c),
// fp16-pair u32 LDS writes, LDS slot-swizzle X(rr)=(hhi*14+ww4)&15 for bank
// spread. Phase B: b128 row reads (conflict-free) + 16B global stores.
// ---------------------------------------------------------------------------
__global__ __launch_bounds__(256) void k_transpose(const float* __restrict__ in,
                                                   _Float16* __restrict__ t2) {
    __shared__ char Lt[4 * 56 * 256];   // 57,344 B
    const int n   = blockIdx.y;
    const int hh0 = blockIdx.x * 4;
    const int t   = threadIdx.x;
    const int lane = t & 63, wid = t >> 6;
    const float4* in4 = (const float4*)in;

    if (lane < 56) {
        const int ww4 = lane % 14, hhi = lane / 14;
        const int X    = lane & 15;                  // == (hhi*14+ww4)&15
        const int rowb = (hhi * 56 + ww4 * 4) * 256;
        const int gbase = ((n * 128) * 56 + hh0 + hhi) * 14 + ww4;
#pragma unroll 4
        for (int p = 0; p < 16; ++p) {
            const int c0 = wid * 32 + p * 2;
            float4 a = in4[gbase + c0 * 56 * 14];
            float4 b = in4[gbase + (c0 + 1) * 56 * 14];
            const int cb = c0 * 2;                   // pair byte offset in row
            const int swz = (cb & 15) | ((((cb >> 4)) ^ X) << 4);
            const float* af = (const float*)&a;
            const float* bf = (const float*)&b;
#pragma unroll
            for (int i = 0; i < 4; ++i)
                *(unsigned*)(Lt + rowb + i * 256 + swz) = pack2(af[i], bf[i]);
        }
    }
    __syncthreads();

    {
        const int j = t & 15;
        int ww = t >> 4, hhi = 0;                    // rr = t>>4 (<16)
        for (int it = 0; it < 14; ++it) {
            const int X  = (hhi * 14 + (ww >> 2)) & 15;
            const int hh = hh0 + hhi;
            const int s  = j ^ (hh & 15) ^ X;
            int4 v = *(const int4*)(Lt + (hhi * 56 + ww) * 256 + s * 16);
            char* dst = (char*)t2 + ((size_t)((n * 56 + ww) * 56 + hh)) * 256 + j * 16;
            *(int4*)dst = v;
            ww += 16; if (ww >= 56) { ww -= 56; ++hhi; }
        }
    }
}

// ---------------------------------------------------------------------------
// Kernel 2 v2: weights fp32 [F][1152] -> Bp[kb][f][kin] fp16, swizzle (f&7)<<4.
// float4 load (perfectly linear: in4[tid]) -> 8B store. Same layout as before.
// ---------------------------------------------------------------------------
__global__ __launch_bounds__(256) void k_weights(const float* __restrict__ kern,
                                                 _Float16* __restrict__ bp) {
    const int tid = blockIdx.x * 256 + threadIdx.x;
    if (tid >= F_OUT * KKDIM / 4) return;            // 73,728
    const float4 v = ((const float4*)kern)[tid];
    const int kq = tid % 288, f = tid / 288;
    const int kb   = kq >> 4;
    const int kin2 = (kq & 15) * 8;                  // byte offset, 8B aligned
    uint2 w; w.x = pack2(v.x, v.y); w.y = pack2(v.z, v.w);
    char* dst = (char*)bp + kb * B_CHUNK + f * 128
              + ((kin2 & 15) | (((kin2 >> 4) ^ (f & 7)) << 4));
    *(uint2*)dst = w;
}

// ---------------------------------------------------------------------------
// Kernel 3: implicit-GEMM MFMA (v2 structure = best measured, 97.9us),
// templated for ablation:
//   VAR 0: full (real kernel, full grid)
//   VAR 1: NOSTAGE — no in-loop B staging / vmcnt (reads stale Bs0)
//   VAR 2: NOLDS   — no in-loop ds_reads (constant frags); staging kept
//   VAR 3: NOEPI   — full loop; epilogue replaced by 1 store/thread
// Ablations run on grid (14,8) writing garbage to d_out; the real <0> runs
// LAST and overwrites every output element.
// ---------------------------------------------------------------------------
typedef const __attribute__((address_space(1))) unsigned int guint;
typedef __attribute__((address_space(3))) unsigned int luint;

template<int VAR>
__global__ __launch_bounds__(1024, 4) void k_gemm_t(const _Float16* __restrict__ t2,
                                                    const _Float16* __restrict__ bp,
                                                    float* __restrict__ out) {
    extern __shared__ char smem[];
    char* As  = smem;
    char* Bs0 = smem + A_REGION;
    char* Bs1 = smem + A_REGION + B_CHUNK;

    const int tid  = threadIdx.x;
    const int lane = tid & 63;
    const int wid  = tid >> 6;       // 0..15
    const int wm   = wid >> 2;       // w-col 0..3
    const int wh   = (wid >> 1) & 1; // h half
    const int wf   = wid & 1;        // f half
    const int ln31 = lane & 31;
    const int kin2 = (lane >> 5) * 16;
    const int n  = blockIdx.y;
    const int w0 = blockIdx.x * 4;

    int navail = 56 - w0; if (navail > 6) navail = 6;
    const int bytesA = navail * SLAB_I_STRIDE;
    const char* t2n = (const char*)t2 + (size_t)(n * 56 + w0) * 56 * 256;
    for (int o = tid * 16; o < bytesA; o += 16384)
        __builtin_amdgcn_global_load_lds((guint*)(t2n + o), (luint*)(As + o), 16, 0, 0);

    const char* bpc = (const char*)bp;
    __builtin_amdgcn_global_load_lds((guint*)(bpc + tid * 16), (luint*)(Bs0 + tid * 16), 16, 0, 0);
    __builtin_amdgcn_global_load_lds((guint*)(bpc + tid * 16 + 16384), (luint*)(Bs0 + tid * 16 + 16384), 16, 0, 0);

    f32x16 acc[4];
#pragma unroll
    for (int ft = 0; ft < 4; ++ft)
#pragma unroll
        for (int e = 0; e < 16; ++e)
            acc[ft][e] = 0.0f;

    const int Xb = (ln31 & 7) << 4;
    const int fb128 = (wf * 128 + ln31) * 128;

    half8 aC, bC;                     // constant frags for VAR 2
    if constexpr (VAR == 2) {
        asm volatile("s_waitcnt vmcnt(0)" ::: "memory");
        ASM_BAR();
        aC = *(const half8*)(As + lane * 16);
        bC = *(const half8*)(Bs0 + lane * 16);
    }

    for (int kb = 0; kb < NKB; ++kb) {
        const char* curB = (VAR == 1) ? Bs0 : ((kb & 1) ? Bs1 : Bs0);
        if constexpr (VAR != 1) {
            if (kb < NKB - 1) {
                char* nxtB = (kb & 1) ? Bs0 : Bs1;
                const char* src = bpc + (kb + 1) * B_CHUNK;
                __builtin_amdgcn_global_load_lds((guint*)(src + tid * 16), (luint*)(nxtB + tid * 16), 16, 0, 0);
                __builtin_amdgcn_global_load_lds((guint*)(src + tid * 16 + 16384), (luint*)(nxtB + tid * 16 + 16384), 16, 0, 0);
                asm volatile("s_waitcnt vmcnt(2)" ::: "memory");
            } else {
                asm volatile("s_waitcnt vmcnt(0)" ::: "memory");
            }
        }
        ASM_BAR();

        const int ij  = kb >> 1;
        const int iq  = ij / 3;
        const int jq  = ij - iq * 3;
        const int ch2 = (kb & 1) * 128;
        const int hh  = wh * 32 + ln31 + jq;
        const int Xa  = (hh & 15) << 4;
        const int abase = (wm + iq) * SLAB_I_STRIDE + hh * 256;

#pragma unroll
        for (int s = 0; s < 4; ++s) {
            half8 aF; half8 bF[4];
            if constexpr (VAR == 2) {
                aF = aC;
#pragma unroll
                for (int ft = 0; ft < 4; ++ft) bF[ft] = bC;
            } else {
                const int cb = ch2 + s * 32 + kin2;
                aF = *(const half8*)(As + abase + (cb ^ Xa));
#pragma unroll
                for (int ft = 0; ft < 4; ++ft)
                    bF[ft] = *(const half8*)(curB + fb128 + ft * 4096 + ((s * 32 + kin2) ^ Xb));
            }
            __builtin_amdgcn_s_setprio(1);
#pragma unroll
            for (int ft = 0; ft < 4; ++ft)
                acc[ft] = __builtin_amdgcn_mfma_f32_32x32x16_f16(aF, bF[ft], acc[ft], 0, 0, 0);
            __builtin_amdgcn_s_setprio(0);
        }
        ASM_BAR();
    }

    if constexpr (VAR == 3) {
        // epilogue ablated: keep acc live with a single store per thread
        float sv = 0.0f;
#pragma unroll
        for (int ft = 0; ft < 4; ++ft)
#pragma unroll
            for (int e = 0; e < 16; ++e) sv += acc[ft][e];
        out[((size_t)n * 14 + blockIdx.x) * 1024 + tid] = sv;
        return;
    }

    const int w = w0 + wm;
    if (w < WO) {
        const int hi4 = (lane >> 5) * 4;
#pragma unroll
        for (int ft = 0; ft < 4; ++ft) {
            const int f = wf * 128 + ft * 32 + ln31;
            float* op = out + ((size_t)(n * 256 + f) * 54 + w) * 54;
#pragma unroll
            for (int q = 0; q < 4; ++q) {
                const int hb = wh * 32 + q * 8 + hi4;
                if (hb + 3 < HO) {
                    f32x4 v = { acc[ft][4 * q + 0], acc[ft][4 * q + 1],
                                acc[ft][4 * q + 2], acc[ft][4 * q + 3] };
                    *(f32x4*)(op + hb) = v;
                } else if (hb < HO) {
                    op[hb]     = acc[ft][4 * q + 0];
                    op[hb + 1] = acc[ft][4 * q + 1];
                }
            }
        }
    }
}

// ---------------------------------------------------------------------------
// Fallback (only if ws too small)
// ---------------------------------------------------------------------------
__global__ __launch_bounds__(256) void k_naive(const float* __restrict__ in,
                                               const float* __restrict__ kern,
                                               float* __restrict__ out) {
    const int idx = blockIdx.x * 256 + threadIdx.x;
    const int total = N_IMG * F_OUT * WO * HO;
    if (idx >= total) return;
    const int h = idx % 54;
    const int w = (idx / 54) % 54;
    const int f = (idx / (54 * 54)) % 256;
    const int n = idx / (54 * 54 * 256);
    float s = 0.f;
    for (int ij = 0; ij < 9; ++ij) {
        const int i = ij / 3, j = ij % 3;
        const float* ip = in + ((size_t)(n * 128) * 56 + (h + j)) * 56 + (w + i);
        const float* kp = kern + (size_t)f * KKDIM + ij * 128;
        for (int c = 0; c < 128; ++c) s += ip[(size_t)c * 3136] * kp[c];
    }
    out[idx] = s;
}

extern "C" void kernel_launch(void* const* d_in, const int* in_sizes, int n_in,
                              void* d_out, int out_size, void* d_ws, size_t ws_size,
                              hipStream_t stream) {
    const float* in   = (const float*)d_in[0];
    const float* kern = (const float*)d_in[1];
    float* out = (float*)d_out;

    if (ws_size < (size_t)WS_NEED) {
        const int total = N_IMG * F_OUT * WO * HO;
        k_naive<<<(total + 255) / 256, 256, 0, stream>>>(in, kern, out);
        return;
    }

    _Float16* t2 = (_Float16*)d_ws;
    _Float16* bp = (_Float16*)((char*)d_ws + BP_OFF);

    k_transpose<<<dim3(14, 32), 256, 0, stream>>>(in, t2);
    k_weights<<<288, 256, 0, stream>>>(kern, bp);

    (void)hipFuncSetAttribute((const void*)k_gemm_t<0>, hipFuncAttributeMaxDynamicSharedMemorySize, SMEM_BYTES);
    (void)hipFuncSetAttribute((const void*)k_gemm_t<1>, hipFuncAttributeMaxDynamicSharedMemorySize, SMEM_BYTES);
    (void)hipFuncSetAttribute((const void*)k_gemm_t<2>, hipFuncAttributeMaxDynamicSharedMemorySize, SMEM_BYTES);
    (void)hipFuncSetAttribute((const void*)k_gemm_t<3>, hipFuncAttributeMaxDynamicSharedMemorySize, SMEM_BYTES);

    // Ablations (quarter grid, throwaway output; real kernel overwrites below)
    k_gemm_t<0><<<dim3(14, 8), 1024, SMEM_BYTES, stream>>>(t2, bp, out);  // control
    k_gemm_t<1><<<dim3(14, 8), 1024, SMEM_BYTES, stream>>>(t2, bp, out);  // NOSTAGE
    k_gemm_t<2><<<dim3(14, 8), 1024, SMEM_BYTES, stream>>>(t2, bp, out);  // NOLDS
    k_gemm_t<3><<<dim3(14, 8), 1024, SMEM_BYTES, stream>>>(t2, bp, out);  // NOEPI

    // Real kernel — last writer of d_out
    k_gemm_t<0><<<dim3(14, 32), 1024, SMEM_BYTES, stream>>>(t2, bp, out);
}

// Round 11
// 223.878 us; speedup vs baseline: 1.5221x; 1.5221x over previous
//
#include <hip/hip_runtime.h>

typedef _Float16 half8 __attribute__((ext_vector_type(8)));
typedef float f32x16 __attribute__((ext_vector_type(16)));

#define N_IMG 32
#define C_IN  128
#define H_IN  56
#define W_IN  56
#define F_OUT 256
#define HO    54
#define WO    54
#define KKDIM 1152
#define NKB   18            // 1152 / 64

#define T2_BYTES (N_IMG * W_IN * H_IN * C_IN * 2)   // 25,690,112
#define BP_OFF   T2_BYTES
#define BP_BYTES (NKB * F_OUT * 64 * 2)             // 589,824
#define WS_NEED  (BP_OFF + BP_BYTES)

#define SLAB_I_STRIDE 14336        // 56 rows * 256 B
#define A_REGION  88576            // padded (h>=54 garbage rows, discarded)
#define B_CHUNK   32768
#define SMEM_BYTES (A_REGION + 2 * B_CHUNK)  // 154112

#define ASM_BAR() asm volatile("s_barrier" ::: "memory")

static __device__ inline unsigned pack2(float a, float b) {
    union { _Float16 h[2]; unsigned u; } x;
    x.h[0] = (_Float16)a; x.h[1] = (_Float16)b; return x.u;
}

// ---------------------------------------------------------------------------
// Kernel 1 v2 (verified R10): NCHW fp32 -> T2[n][ww][hh][c] fp16, slot j of a
// 256B c-row holds c-group j^(hh&15).
// ---------------------------------------------------------------------------
__global__ __launch_bounds__(256) void k_transpose(const float* __restrict__ in,
                                                   _Float16* __restrict__ t2) {
    __shared__ char Lt[4 * 56 * 256];   // 57,344 B
    const int n   = blockIdx.y;
    const int hh0 = blockIdx.x * 4;
    const int t   = threadIdx.x;
    const int lane = t & 63, wid = t >> 6;
    const float4* in4 = (const float4*)in;

    if (lane < 56) {
        const int ww4 = lane % 14, hhi = lane / 14;
        const int X    = lane & 15;
        const int rowb = (hhi * 56 + ww4 * 4) * 256;
        const int gbase = ((n * 128) * 56 + hh0 + hhi) * 14 + ww4;
#pragma unroll 4
        for (int p = 0; p < 16; ++p) {
            const int c0 = wid * 32 + p * 2;
            float4 a = in4[gbase + c0 * 56 * 14];
            float4 b = in4[gbase + (c0 + 1) * 56 * 14];
            const int cb = c0 * 2;
            const int swz = (cb & 15) | ((((cb >> 4)) ^ X) << 4);
            const float* af = (const float*)&a;
            const float* bf = (const float*)&b;
#pragma unroll
            for (int i = 0; i < 4; ++i)
                *(unsigned*)(Lt + rowb + i * 256 + swz) = pack2(af[i], bf[i]);
        }
    }
    __syncthreads();

    {
        const int j = t & 15;
        int ww = t >> 4, hhi = 0;
        for (int it = 0; it < 14; ++it) {
            const int X  = (hhi * 14 + (ww >> 2)) & 15;
            const int hh = hh0 + hhi;
            const int s  = j ^ (hh & 15) ^ X;
            int4 v = *(const int4*)(Lt + (hhi * 56 + ww) * 256 + s * 16);
            char* dst = (char*)t2 + ((size_t)((n * 56 + ww) * 56 + hh)) * 256 + j * 16;
            *(int4*)dst = v;
            ww += 16; if (ww >= 56) { ww -= 56; ++hhi; }
        }
    }
}

// ---------------------------------------------------------------------------
// Kernel 2 v2 (verified R10): weights fp32 [F][1152] -> Bp[kb][f][kin] fp16,
// row swizzle (f&7)<<4.
// ---------------------------------------------------------------------------
__global__ __launch_bounds__(256) void k_weights(const float* __restrict__ kern,
                                                 _Float16* __restrict__ bp) {
    const int tid = blockIdx.x * 256 + threadIdx.x;
    if (tid >= F_OUT * KKDIM / 4) return;
    const float4 v = ((const float4*)kern)[tid];
    const int kq = tid % 288, f = tid / 288;
    const int kb   = kq >> 4;
    const int kin2 = (kq & 15) * 8;
    uint2 w; w.x = pack2(v.x, v.y); w.y = pack2(v.z, v.w);
    char* dst = (char*)bp + kb * B_CHUNK + f * 128
              + ((kin2 & 15) | (((kin2 >> 4) ^ (f & 7)) << 4));
    *(uint2*)dst = w;
}

// ---------------------------------------------------------------------------
// Kernel 3 v5: implicit-GEMM MFMA, 8 waves (512 thr), wave = 64h x 128f.
// NEW vs v1/v2 (same 2-phase counted-vmcnt chunk frame):
//  (a) s-loop REGISTER PIPELINE: fragments for k-step s+1 are ds_read while
//      MFMA cluster s runs (2-set static rotation) — hides LDS latency that
//      the barrier-locked burst pattern exposed (measured 28% MfmaUtil with
//      MFMA needing only ~30% of chunk time).
//  (b) SWAPPED OPERANDS mfma(bF, aF): D col(lane&31) = h -> epilogue stores
//      are 32-lane contiguous (2x128B per instr), killing the 32-line scatter
//      and the 1.3x write amplification (125 -> ~96 MB).
// ---------------------------------------------------------------------------
typedef const __attribute__((address_space(1))) unsigned int guint;
typedef __attribute__((address_space(3))) unsigned int luint;

#define LDA_(S, A0, A1) do { \
    const int cb_ = ch2 + (S)*32 + kin2; \
    A0 = *(const half8*)(As + abase + (cb_ ^ Xa)); \
    A1 = *(const half8*)(As + abase + 8192 + (cb_ ^ Xa)); } while(0)

#define LDB_(S, B0, B1, B2, B3) do { \
    const int ob_ = (((S)*32 + kin2) ^ Xb); \
    B0 = *(const half8*)(curB + fb128 + ob_); \
    B1 = *(const half8*)(curB + fb128 + 4096 + ob_); \
    B2 = *(const half8*)(curB + fb128 + 8192 + ob_); \
    B3 = *(const half8*)(curB + fb128 + 12288 + ob_); } while(0)

#define MM_(A0, A1, B0, B1, B2, B3) do { \
    __builtin_amdgcn_s_setprio(1); \
    acc[0][0] = __builtin_amdgcn_mfma_f32_32x32x16_f16(B0, A0, acc[0][0], 0, 0, 0); \
    acc[1][0] = __builtin_amdgcn_mfma_f32_32x32x16_f16(B0, A1, acc[1][0], 0, 0, 0); \
    acc[0][1] = __builtin_amdgcn_mfma_f32_32x32x16_f16(B1, A0, acc[0][1], 0, 0, 0); \
    acc[1][1] = __builtin_amdgcn_mfma_f32_32x32x16_f16(B1, A1, acc[1][1], 0, 0, 0); \
    acc[0][2] = __builtin_amdgcn_mfma_f32_32x32x16_f16(B2, A0, acc[0][2], 0, 0, 0); \
    acc[1][2] = __builtin_amdgcn_mfma_f32_32x32x16_f16(B2, A1, acc[1][2], 0, 0, 0); \
    acc[0][3] = __builtin_amdgcn_mfma_f32_32x32x16_f16(B3, A0, acc[0][3], 0, 0, 0); \
    acc[1][3] = __builtin_amdgcn_mfma_f32_32x32x16_f16(B3, A1, acc[1][3], 0, 0, 0); \
    __builtin_amdgcn_s_setprio(0); } while(0)

__global__ __launch_bounds__(512, 2) void k_gemm(const _Float16* __restrict__ t2,
                                                 const _Float16* __restrict__ bp,
                                                 float* __restrict__ out) {
    extern __shared__ char smem[];
    char* As  = smem;
    char* Bs0 = smem + A_REGION;
    char* Bs1 = smem + A_REGION + B_CHUNK;

    const int tid  = threadIdx.x;
    const int lane = tid & 63;
    const int wid  = tid >> 6;       // 0..7
    const int wm   = wid >> 1;       // w-col 0..3
    const int wf   = wid & 1;        // f half (128 cols)
    const int ln31 = lane & 31;
    const int kin2 = (lane >> 5) * 16;
    const int n  = blockIdx.y;
    const int w0 = blockIdx.x * 4;

    // ---- prologue: stage A slab + B chunk 0 ----
    int navail = 56 - w0; if (navail > 6) navail = 6;
    const int bytesA = navail * SLAB_I_STRIDE;
    const char* t2n = (const char*)t2 + (size_t)(n * 56 + w0) * 56 * 256;
    for (int o = tid * 16; o < bytesA; o += 8192)   // wave-uniform trips
        __builtin_amdgcn_global_load_lds((guint*)(t2n + o), (luint*)(As + o), 16, 0, 0);

    const char* bpc = (const char*)bp;
#pragma unroll
    for (int q = 0; q < 4; ++q)
        __builtin_amdgcn_global_load_lds((guint*)(bpc + tid * 16 + q * 8192),
                                         (luint*)(Bs0 + tid * 16 + q * 8192), 16, 0, 0);

    f32x16 acc[2][4];
#pragma unroll
    for (int m2 = 0; m2 < 2; ++m2)
#pragma unroll
        for (int ft = 0; ft < 4; ++ft)
#pragma unroll
            for (int e = 0; e < 16; ++e)
                acc[m2][ft][e] = 0.0f;

    asm volatile("s_waitcnt vmcnt(0)" ::: "memory");
    ASM_BAR();

    const int Xb = (ln31 & 7) << 4;
    const int fb128 = (wf * 128 + ln31) * 128;

    for (int kb = 0; kb < NKB; ++kb) {
        const char* curB = (kb & 1) ? Bs1 : Bs0;
        if (kb < NKB - 1) {
            // prefetch next B chunk (4 loads/thread), counted wait: the 4 just
            // issued stay in flight; everything older (this chunk's B) retires
            char* nxtB = (kb & 1) ? Bs0 : Bs1;
            const char* src = bpc + (kb + 1) * B_CHUNK;
#pragma unroll
            for (int q = 0; q < 4; ++q)
                __builtin_amdgcn_global_load_lds((guint*)(src + tid * 16 + q * 8192),
                                                 (luint*)(nxtB + tid * 16 + q * 8192), 16, 0, 0);
            asm volatile("s_waitcnt vmcnt(4)" ::: "memory");
        } else {
            asm volatile("s_waitcnt vmcnt(0)" ::: "memory");
        }
        ASM_BAR();   // all waves' B(kb) (and at kb=0 the A slab) resident

        const int ij  = kb >> 1;
        const int iq  = ij / 3;            // w-offset
        const int jq  = ij - iq * 3;       // h-offset
        const int ch2 = (kb & 1) * 128;    // c byte offset of this 64-k chunk
        const int hh0 = ln31 + jq;
        const int Xa  = (hh0 & 15) << 4;   // +32 rows doesn't change &15
        const int abase = (wm + iq) * SLAB_I_STRIDE + hh0 * 256;

        // ---- register-pipelined k16 steps: load s+1 while MFMA'ing s ----
        half8 xa0, xa1, xb0, xb1, xb2, xb3;
        half8 ya0, ya1, yb0, yb1, yb2, yb3;
        LDA_(0, xa0, xa1); LDB_(0, xb0, xb1, xb2, xb3);
        LDA_(1, ya0, ya1); LDB_(1, yb0, yb1, yb2, yb3);
        MM_(xa0, xa1, xb0, xb1, xb2, xb3);
        LDA_(2, xa0, xa1); LDB_(2, xb0, xb1, xb2, xb3);
        MM_(ya0, ya1, yb0, yb1, yb2, yb3);
        LDA_(3, ya0, ya1); LDB_(3, yb0, yb1, yb2, yb3);
        MM_(xa0, xa1, xb0, xb1, xb2, xb3);
        MM_(ya0, ya1, yb0, yb1, yb2, yb3);

        ASM_BAR();   // reads of curB retired; next iteration may overwrite
    }

    // ---- epilogue (swapped D): col(lane&31)=h, row(reg)=f_local:
    //      f_local = (e&3) + 8*(e>>2) + 4*(lane>>5)
    const int w = w0 + wm;
    if (w < WO) {
        float* opb = out + ((size_t)(n * 256 + wf * 128) * 54 + w) * 54;
        const int f4 = (lane >> 5) * 4;
#pragma unroll
        for (int m2 = 0; m2 < 2; ++m2) {
            const int h = m2 * 32 + ln31;
            if (h < HO) {
#pragma unroll
                for (int ft = 0; ft < 4; ++ft) {
#pragma unroll
                    for (int e = 0; e < 16; ++e) {
                        const int fl = ft * 32 + (e & 3) + 8 * (e >> 2) + f4;
                        opb[(size_t)fl * 2916 + h] = acc[m2][ft][e];
                    }
                }
            }
        }
    }
}

// ---------------------------------------------------------------------------
// Fallback (only if ws too small)
// ---------------------------------------------------------------------------
__global__ __launch_bounds__(256) void k_naive(const float* __restrict__ in,
                                               const float* __restrict__ kern,
                                               float* __restrict__ out) {
    const int idx = blockIdx.x * 256 + threadIdx.x;
    const int total = N_IMG * F_OUT * WO * HO;
    if (idx >= total) return;
    const int h = idx % 54;
    const int w = (idx / 54) % 54;
    const int f = (idx / (54 * 54)) % 256;
    const int n = idx / (54 * 54 * 256);
    float s = 0.f;
    for (int ij = 0; ij < 9; ++ij) {
        const int i = ij / 3, j = ij % 3;
        const float* ip = in + ((size_t)(n * 128) * 56 + (h + j)) * 56 + (w + i);
        const float* kp = kern + (size_t)f * KKDIM + ij * 128;
        for (int c = 0; c < 128; ++c) s += ip[(size_t)c * 3136] * kp[c];
    }
    out[idx] = s;
}

extern "C" void kernel_launch(void* const* d_in, const int* in_sizes, int n_in,
                              void* d_out, int out_size, void* d_ws, size_t ws_size,
                              hipStream_t stream) {
    const float* in   = (const float*)d_in[0];
    const float* kern = (const float*)d_in[1];
    float* out = (float*)d_out;

    if (ws_size < (size_t)WS_NEED) {
        const int total = N_IMG * F_OUT * WO * HO;
        k_naive<<<(total + 255) / 256, 256, 0, stream>>>(in, kern, out);
        return;
    }

    _Float16* t2 = (_Float16*)d_ws;
    _Float16* bp = (_Float16*)((char*)d_ws + BP_OFF);

    k_transpose<<<dim3(14, 32), 256, 0, stream>>>(in, t2);
    k_weights<<<288, 256, 0, stream>>>(kern, bp);

    (void)hipFuncSetAttribute((const void*)k_gemm,
                              hipFuncAttributeMaxDynamicSharedMemorySize, SMEM_BYTES);
    k_gemm<<<dim3(14, 32), 512, SMEM_BYTES, stream>>>(t2, bp, out);
}